// Round 1
// baseline (368.694 us; speedup 1.0000x reference)
//
#include <hip/hip_runtime.h>

// ---------------------------------------------------------------------------
// MemoryAttention: B=2 Q=1024 K=2048 M=1024 E=1024 H=32 HD=32
//   qp   = (query @ Wq^T + bq) * SCALE          (bf16, 2048x1024)
//   kcat = (concat(key,mem) @ Wk^T + bk)        (bf16, 6144x1024)  [per-batch concat]
//   vcat = (concat(value,mem) @ Wv^T + bv)      (bf16, 6144x1024)
//   vT   = transpose per (b,h): (b,h,d,l)       (bf16, 2048x3072)
//   attn = softmax(qp kcat^T) vcat              (fp32, 2048x1024)
//   out  = attn @ Wo^T + bo                     (fp32 -> d_out)
// ---------------------------------------------------------------------------

typedef float  f32x4  __attribute__((ext_vector_type(4)));
typedef short  bf16x8 __attribute__((ext_vector_type(8)));
typedef unsigned int   u32;
typedef unsigned short u16;
typedef u32 u32x4 __attribute__((ext_vector_type(4)));
typedef u16 u16x4 __attribute__((ext_vector_type(4)));
typedef u16 u16x8 __attribute__((ext_vector_type(8)));

#define SCALE_  0.17677669529663687f   // 32^-0.5
#define LOG2E_  1.4426950408889634f

// round-half-up fp32->bf16 (inputs are well-scaled normals; no NaN/Inf path)
static __device__ __forceinline__ u32 bfpack2(float lo, float hi) {
  u32 a = __builtin_bit_cast(u32, lo) + 0x8000u;
  u32 b = __builtin_bit_cast(u32, hi) + 0x8000u;
  // out = {a.b2,a.b3,b.b2,b.b3} : low u16 = bf16(lo), high u16 = bf16(hi)
  return __builtin_amdgcn_perm(b, a, 0x07060302u);
}
static __device__ __forceinline__ u16 bf16of(float x) {
  return (u16)((__builtin_bit_cast(u32, x) + 0x8000u) >> 16);
}

// ---------------------------------------------------------------------------
// GEMM:  C[m,n] = (sum_k A[m,k] * W[n,k] + bias[n]) * scale
// A rows come from two per-batch segments P0 (L0 rows/batch) then P1 (L1).
// 128x128 tile, BK=64, 256 thr = 4 waves (2x2), each wave 64x64 = 4x4 MFMA.
// fp32 global -> bf16 LDS (packed in regs), register prefetch of next K-step.
// ---------------------------------------------------------------------------
template <int OUT_BF16>
__global__ __launch_bounds__(256, 2)
void gemm_nt_kernel(const float* __restrict__ P0, int L0,
                    const float* __restrict__ P1, int L1,
                    const float* __restrict__ W,
                    const float* __restrict__ bias,
                    void* __restrict__ Cout,
                    float scale) {
  constexpr int Kd = 1024, N = 1024;
  __shared__ u16 As[128 * 64];
  __shared__ u16 Bs[128 * 64];

  const int tid  = threadIdx.x;
  const int lane = tid & 63;
  const int wave = tid >> 6;
  const int ln   = lane & 15;
  const int quad = lane >> 4;
  const int wm   = wave >> 1;
  const int wn   = wave & 1;
  const int bm = blockIdx.x, bn = blockIdx.y;

  // tile never crosses a segment boundary (128 | 1024,2048,3072)
  const int gr0 = bm * 128;
  const int per = L0 + L1;
  const int bb  = gr0 / per;
  const int i0  = gr0 - bb * per;
  const float* Abase = (i0 < L0) ? (P0 + (size_t)(bb * L0 + i0) * Kd)
                                 : (P1 + (size_t)(bb * L1 + (i0 - L0)) * Kd);
  const float* Wbase = W + (size_t)(bn * 128) * Kd;

  // per-thread staging coords: 4 chunk-pairs of 8 floats each, per tile
  const int srow[4]  = { (tid + 0) >> 3, (tid + 256) >> 3, (tid + 512) >> 3, (tid + 768) >> 3 };
  const int scolf    = (tid & 7) << 3;

  f32x4 acc[4][4];
#pragma unroll
  for (int i = 0; i < 4; ++i)
#pragma unroll
    for (int j = 0; j < 4; ++j)
      acc[i][j] = (f32x4){0.f, 0.f, 0.f, 0.f};

  f32x4 ra[4][2], rw[4][2];
  // preload kt = 0
#pragma unroll
  for (int p = 0; p < 4; ++p) {
    const float* sa = Abase + (size_t)srow[p] * Kd + scolf;
    const float* sw = Wbase + (size_t)srow[p] * Kd + scolf;
    ra[p][0] = *(const f32x4*)sa; ra[p][1] = *(const f32x4*)(sa + 4);
    rw[p][0] = *(const f32x4*)sw; rw[p][1] = *(const f32x4*)(sw + 4);
  }

  for (int kt = 0; kt < Kd; kt += 64) {
    // convert + store to LDS
#pragma unroll
    for (int p = 0; p < 4; ++p) {
      u32x4 pa, pw;
      pa.x = bfpack2(ra[p][0].x, ra[p][0].y); pa.y = bfpack2(ra[p][0].z, ra[p][0].w);
      pa.z = bfpack2(ra[p][1].x, ra[p][1].y); pa.w = bfpack2(ra[p][1].z, ra[p][1].w);
      pw.x = bfpack2(rw[p][0].x, rw[p][0].y); pw.y = bfpack2(rw[p][0].z, rw[p][0].w);
      pw.z = bfpack2(rw[p][1].x, rw[p][1].y); pw.w = bfpack2(rw[p][1].z, rw[p][1].w);
      *(u32x4*)&As[srow[p] * 64 + scolf] = pa;
      *(u32x4*)&Bs[srow[p] * 64 + scolf] = pw;
    }
    __syncthreads();

    // prefetch next K-step while MFMAs run
    const int ktn = (kt + 64 < Kd) ? (kt + 64) : 0;
#pragma unroll
    for (int p = 0; p < 4; ++p) {
      const float* sa = Abase + (size_t)srow[p] * Kd + ktn + scolf;
      const float* sw = Wbase + (size_t)srow[p] * Kd + ktn + scolf;
      ra[p][0] = *(const f32x4*)sa; ra[p][1] = *(const f32x4*)(sa + 4);
      rw[p][0] = *(const f32x4*)sw; rw[p][1] = *(const f32x4*)(sw + 4);
    }

#pragma unroll
    for (int kk = 0; kk < 2; ++kk) {
      bf16x8 af[4], bfr[4];
#pragma unroll
      for (int mi = 0; mi < 4; ++mi)
        af[mi] = *(const bf16x8*)&As[(wm * 64 + mi * 16 + ln) * 64 + kk * 32 + quad * 8];
#pragma unroll
      for (int ni = 0; ni < 4; ++ni)
        bfr[ni] = *(const bf16x8*)&Bs[(wn * 64 + ni * 16 + ln) * 64 + kk * 32 + quad * 8];
#pragma unroll
      for (int mi = 0; mi < 4; ++mi)
#pragma unroll
        for (int ni = 0; ni < 4; ++ni)
          acc[mi][ni] = __builtin_amdgcn_mfma_f32_16x16x32_bf16(af[mi], bfr[ni], acc[mi][ni], 0, 0, 0);
    }
    __syncthreads();
  }

  // epilogue: C/D layout col=lane&15, row=quad*4+reg
#pragma unroll
  for (int ni = 0; ni < 4; ++ni) {
    const int gc = bn * 128 + wn * 64 + ni * 16 + ln;
    const float bval = bias[gc];
#pragma unroll
    for (int mi = 0; mi < 4; ++mi) {
      const int gr = bm * 128 + wm * 64 + mi * 16 + quad * 4;
#pragma unroll
      for (int r = 0; r < 4; ++r) {
        const float v = (acc[mi][ni][r] + bval) * scale;
        if (OUT_BF16)
          ((u16*)Cout)[(size_t)(gr + r) * N + gc] = bf16of(v);
        else
          ((float*)Cout)[(size_t)(gr + r) * N + gc] = v;
      }
    }
  }
}

// ---------------------------------------------------------------------------
// Transpose vcat (b*3072+l, h*32+d) -> vT[(b,h,d), l]  (bf16)
// tile: 128 l-rows x 32 d-cols via LDS
// ---------------------------------------------------------------------------
__global__ __launch_bounds__(256)
void transpose_v_kernel(const u16* __restrict__ vcat, u16* __restrict__ vT) {
  __shared__ u16 T[32][132];
  const int tid = threadIdx.x;
  const int l0  = blockIdx.x * 128;
  const int bh  = blockIdx.y;
  const int b   = bh >> 5, h = bh & 31;

#pragma unroll
  for (int j = 0; j < 4; ++j) {
    const int c = tid + 256 * j;       // 1024 u16x4 chunks
    const int row  = c >> 3;           // 0..127 (l)
    const int col4 = (c & 7) * 4;      // 0..28 (d)
    u16x4 v = *(const u16x4*)&vcat[(size_t)(b * 3072 + l0 + row) * 1024 + h * 32 + col4];
    T[col4 + 0][row] = v.x; T[col4 + 1][row] = v.y;
    T[col4 + 2][row] = v.z; T[col4 + 3][row] = v.w;
  }
  __syncthreads();
#pragma unroll
  for (int j = 0; j < 4; ++j) {
    const int c = tid + 256 * j;
    const int d  = c >> 5;             // 0..31
    const int l4 = (c & 31) * 4;       // 0..124
    u16x4 v;
    v.x = T[d][l4]; v.y = T[d][l4 + 1]; v.z = T[d][l4 + 2]; v.w = T[d][l4 + 3];
    *(u16x4*)&vT[(size_t)(bh * 32 + d) * 3072 + l0 + l4] = v;
  }
}

// ---------------------------------------------------------------------------
// Attention: block = (b,h, 128 q-rows), 4 waves x 32 q-rows, 64-key chunks.
// Scores bounded (|s|<~3) -> max-free softmax: p=exp2(s*log2e), divide by sum.
// P goes C-layout -> LDS (stride 72 u16, padded) -> A-layout for PV.
// ---------------------------------------------------------------------------
__global__ __launch_bounds__(256, 2)
void attn_kernel(const u16* __restrict__ qp,
                 const u16* __restrict__ kcat,
                 const u16* __restrict__ vT,
                 float* __restrict__ outp) {
  __shared__ u16 Ks[64 * 32];
  __shared__ u16 Vs[32 * 64];
  __shared__ u16 Ps[4 * 32 * 72];

  const int tid  = threadIdx.x;
  const int lane = tid & 63;
  const int wave = tid >> 6;
  const int ln   = lane & 15;
  const int quad = lane >> 4;
  const int bh   = blockIdx.x;
  const int b    = bh >> 5;
  const int h    = bh & 31;
  const int q0   = blockIdx.y * 128 + wave * 32;

  // Q A-frags straight from global (A[m=ln][k=quad*8+j], k = head dim 0..31)
  bf16x8 qf[2];
#pragma unroll
  for (int mf = 0; mf < 2; ++mf)
    qf[mf] = *(const bf16x8*)&qp[(size_t)(b * 1024 + q0 + mf * 16 + ln) * 1024 + h * 32 + quad * 8];

  float l_run[2][4];
  f32x4 acc[2][2];
#pragma unroll
  for (int mf = 0; mf < 2; ++mf) {
#pragma unroll
    for (int r = 0; r < 4; ++r) l_run[mf][r] = 0.f;
#pragma unroll
    for (int df = 0; df < 2; ++df) acc[mf][df] = (f32x4){0.f, 0.f, 0.f, 0.f};
  }
  u16* Pw = &Ps[wave * (32 * 72)];

  const int krow = tid >> 2, kcol = (tid & 3) << 3;   // 64 rows x 32 cols
  const int vrow = tid >> 3, vcol = (tid & 7) << 3;   // 32 rows x 64 cols
  const size_t kbase = (size_t)(b * 3072) * 1024 + h * 32;
  const size_t vbase = (size_t)(bh * 32) * 3072;

  u16x8 kv = *(const u16x8*)&kcat[kbase + (size_t)krow * 1024 + kcol];
  u16x8 vv = *(const u16x8*)&vT[vbase + (size_t)vrow * 3072 + vcol];

  for (int c0 = 0; c0 < 3072; c0 += 64) {
    *(u16x8*)&Ks[krow * 32 + kcol] = kv;
    *(u16x8*)&Vs[vrow * 64 + vcol] = vv;
    __syncthreads();

    // prefetch next chunk (wrap to 0 on last iter to stay in-bounds)
    const int cn = (c0 + 64 < 3072) ? (c0 + 64) : 0;
    kv = *(const u16x8*)&kcat[kbase + (size_t)(cn + krow) * 1024 + kcol];
    vv = *(const u16x8*)&vT[vbase + (size_t)vrow * 3072 + cn + vcol];

    // S = Q K^T  (K-dim = HD = 32, one MFMA per 16x16 tile)
    bf16x8 kf[4];
#pragma unroll
    for (int nf = 0; nf < 4; ++nf)
      kf[nf] = *(const bf16x8*)&Ks[(nf * 16 + ln) * 32 + quad * 8];
    f32x4 s[2][4];
#pragma unroll
    for (int mf = 0; mf < 2; ++mf)
#pragma unroll
      for (int nf = 0; nf < 4; ++nf)
        s[mf][nf] = __builtin_amdgcn_mfma_f32_16x16x32_bf16(qf[mf], kf[nf],
                                                            (f32x4){0.f, 0.f, 0.f, 0.f}, 0, 0, 0);

    // softmax numerator + row-sum (C-layout: col=ln, row=quad*4+r)
#pragma unroll
    for (int mf = 0; mf < 2; ++mf) {
      float rs[4] = {0.f, 0.f, 0.f, 0.f};
#pragma unroll
      for (int nf = 0; nf < 4; ++nf)
#pragma unroll
        for (int r = 0; r < 4; ++r) {
          const float p = exp2f(s[mf][nf][r] * LOG2E_);
          rs[r] += p;
          Pw[(mf * 16 + quad * 4 + r) * 72 + nf * 16 + ln] = bf16of(p);
        }
#pragma unroll
      for (int off = 8; off >= 1; off >>= 1)
#pragma unroll
        for (int r = 0; r < 4; ++r)
          rs[r] += __shfl_xor(rs[r], off, 16);
#pragma unroll
      for (int r = 0; r < 4; ++r) l_run[mf][r] += rs[r];
    }

    // O += P V   (within-wave LDS write->read; compiler inserts lgkmcnt)
#pragma unroll
    for (int kk = 0; kk < 2; ++kk) {
      bf16x8 vf[2];
#pragma unroll
      for (int df = 0; df < 2; ++df)
        vf[df] = *(const bf16x8*)&Vs[(df * 16 + ln) * 64 + kk * 32 + quad * 8];
#pragma unroll
      for (int mf = 0; mf < 2; ++mf) {
        bf16x8 pf = *(const bf16x8*)&Pw[(mf * 16 + ln) * 72 + kk * 32 + quad * 8];
#pragma unroll
        for (int df = 0; df < 2; ++df)
          acc[mf][df] = __builtin_amdgcn_mfma_f32_16x16x32_bf16(pf, vf[df], acc[mf][df], 0, 0, 0);
      }
    }
    __syncthreads();
  }

  // out layout (b, q, h*32+d) fp32
#pragma unroll
  for (int mf = 0; mf < 2; ++mf)
#pragma unroll
    for (int r = 0; r < 4; ++r) {
      const float inv = 1.0f / l_run[mf][r];
      const size_t orow = (size_t)(b * 1024 + q0 + mf * 16 + quad * 4 + r) * 1024 + h * 32;
#pragma unroll
      for (int df = 0; df < 2; ++df)
        outp[orow + df * 16 + ln] = acc[mf][df][r] * inv;
    }
}

// ---------------------------------------------------------------------------
extern "C" void kernel_launch(void* const* d_in, const int* in_sizes, int n_in,
                              void* d_out, int out_size, void* d_ws, size_t ws_size,
                              hipStream_t stream) {
  (void)in_sizes; (void)n_in; (void)out_size; (void)ws_size;
  const float* query  = (const float*)d_in[0];
  const float* key    = (const float*)d_in[1];
  const float* value  = (const float*)d_in[2];
  const float* memory = (const float*)d_in[3];
  const float* Wq = (const float*)d_in[4];
  const float* bq = (const float*)d_in[5];
  const float* Wk = (const float*)d_in[6];
  const float* bk = (const float*)d_in[7];
  const float* Wv = (const float*)d_in[8];
  const float* bv = (const float*)d_in[9];
  const float* Wo = (const float*)d_in[10];
  const float* bo = (const float*)d_in[11];
  float* out = (float*)d_out;

  // workspace layout (48 MB total)
  char* ws = (char*)d_ws;
  u16*   qp       = (u16*)(ws);                                   //  4 MB
  u16*   kcat     = (u16*)(ws + (size_t)4  * 1024 * 1024);        // 12 MB
  u16*   vcat     = (u16*)(ws + (size_t)16 * 1024 * 1024);        // 12 MB
  u16*   vT       = (u16*)(ws + (size_t)28 * 1024 * 1024);        // 12 MB
  float* attn_out = (float*)(ws + (size_t)40 * 1024 * 1024);      //  8 MB

  dim3 blk(256);
  // qp = (query Wq^T + bq) * SCALE
  gemm_nt_kernel<1><<<dim3(16, 8), blk, 0, stream>>>(query, 1024, nullptr, 0, Wq, bq, qp, SCALE_);
  // kcat = concat(key, memory) Wk^T + bk
  gemm_nt_kernel<1><<<dim3(48, 8), blk, 0, stream>>>(key, 2048, memory, 1024, Wk, bk, kcat, 1.0f);
  // vcat = concat(value, memory) Wv^T + bv
  gemm_nt_kernel<1><<<dim3(48, 8), blk, 0, stream>>>(value, 2048, memory, 1024, Wv, bv, vcat, 1.0f);
  // vT for PV B-operand
  transpose_v_kernel<<<dim3(24, 64), blk, 0, stream>>>(vcat, vT);
  // attention
  attn_kernel<<<dim3(64, 8), blk, 0, stream>>>(qp, kcat, vT, attn_out);
  // out = attn Wo^T + bo
  gemm_nt_kernel<0><<<dim3(16, 8), blk, 0, stream>>>(attn_out, 2048, nullptr, 0, Wo, bo, (void*)out, 1.0f);
}

// Round 2
// 326.086 us; speedup vs baseline: 1.1307x; 1.1307x over previous
//
#include <hip/hip_runtime.h>

// ---------------------------------------------------------------------------
// MemoryAttention: B=2 Q=1024 K=2048 M=1024 E=1024 H=32 HD=32
//   qp   = (query @ Wq^T + bq) * SCALE * LOG2E   (bf16, 2048x1024)
//   kcat = (concat(key,mem) @ Wk^T + bk)         (bf16, 6144x1024)
//   vcat = (concat(value,mem) @ Wv^T + bv)       (bf16, 6144x1024)
//   vT   = per-(b,h) transpose, key axis chunk-permuted by pi (bf16)
//   attn = softmax(qp kcat^T) vcat               (bf16, 2048x1024)
//   out  = attn @ Wo^T + bo                      (fp32 -> d_out)
// pi(key) = (key&15)*4 + (key>>4) within each 64-key chunk; applied to BOTH
// P's LDS layout and vT's column order -> PV dot product invariant.
// ---------------------------------------------------------------------------

typedef float  f32x4  __attribute__((ext_vector_type(4)));
typedef short  bf16x8 __attribute__((ext_vector_type(8)));
typedef unsigned int   u32;
typedef unsigned short u16;
typedef u32 u32x4 __attribute__((ext_vector_type(4)));
typedef u16 u16x4 __attribute__((ext_vector_type(4)));
typedef u16 u16x8 __attribute__((ext_vector_type(8)));

#define SCALE_  0.17677669529663687f   // 32^-0.5
#define LOG2E_  1.4426950408889634f

static __device__ __forceinline__ u32 bfpack2(float lo, float hi) {
  u32 a = __builtin_bit_cast(u32, lo) + 0x8000u;
  u32 b = __builtin_bit_cast(u32, hi) + 0x8000u;
  return __builtin_amdgcn_perm(b, a, 0x07060302u);
}
static __device__ __forceinline__ u16 bf16of(float x) {
  return (u16)((__builtin_bit_cast(u32, x) + 0x8000u) >> 16);
}

// ---------------------------------------------------------------------------
// GEMM:  C[m,n] = (sum_k A[m,k] * W[n,k] + bias[n]) * scale
// A rows from two per-batch segments P0 (L0 rows/batch) then P1 (L1).
// 128x128 tile, BK=64, 4 waves, 4x4 16x16x32 MFMA per wave.
// LDS stride 72 u16 (144 B): frag-read bank pattern (4*ln+16kk+4quad)%32
// -> 2-way only (free). A dtype templated (fp32 w/ pack, or bf16 direct).
// ---------------------------------------------------------------------------
template <int A_BF16, int OUT_BF16>
__global__ __launch_bounds__(256, 2)
void gemm_nt_kernel(const void* __restrict__ P0_, int L0,
                    const void* __restrict__ P1_, int L1,
                    const float* __restrict__ W,
                    const float* __restrict__ bias,
                    void* __restrict__ Cout,
                    float scale) {
  constexpr int Kd = 1024, N = 1024, LDT = 72;
  __shared__ u16 As[128 * LDT];
  __shared__ u16 Bs[128 * LDT];

  const int tid  = threadIdx.x;
  const int lane = tid & 63;
  const int wave = tid >> 6;
  const int ln   = lane & 15;
  const int quad = lane >> 4;
  const int wm   = wave >> 1;
  const int wn   = wave & 1;
  const int bm = blockIdx.x, bn = blockIdx.y;

  // tile never crosses a segment boundary (128 | 1024,2048,3072)
  const int gr0 = bm * 128;
  const int per = L0 + L1;
  const int bb  = gr0 / per;
  const int i0  = gr0 - bb * per;
  const void* Aseg = (i0 < L0) ? P0_ : P1_;
  const size_t rb  = (i0 < L0) ? (size_t)(bb * L0 + i0)
                               : (size_t)(bb * L1 + (i0 - L0));
  const float* Wbase = W + (size_t)(bn * 128) * Kd;

  const int srow[4]  = { (tid + 0) >> 3, (tid + 256) >> 3, (tid + 512) >> 3, (tid + 768) >> 3 };
  const int scolf    = (tid & 7) << 3;

  f32x4 acc[4][4];
#pragma unroll
  for (int i = 0; i < 4; ++i)
#pragma unroll
    for (int j = 0; j < 4; ++j)
      acc[i][j] = (f32x4){0.f, 0.f, 0.f, 0.f};

  f32x4 raf[4][2], rwf[4][2];
  u16x8 rab[4];

#pragma unroll
  for (int p = 0; p < 4; ++p) {
    if (A_BF16) {
      rab[p] = *(const u16x8*)((const u16*)Aseg + (rb + srow[p]) * Kd + scolf);
    } else {
      const float* sa = (const float*)Aseg + (rb + srow[p]) * Kd + scolf;
      raf[p][0] = *(const f32x4*)sa; raf[p][1] = *(const f32x4*)(sa + 4);
    }
    const float* sw = Wbase + (size_t)srow[p] * Kd + scolf;
    rwf[p][0] = *(const f32x4*)sw; rwf[p][1] = *(const f32x4*)(sw + 4);
  }

  for (int kt = 0; kt < Kd; kt += 64) {
#pragma unroll
    for (int p = 0; p < 4; ++p) {
      if (A_BF16) {
        *(u16x8*)&As[srow[p] * LDT + scolf] = rab[p];
      } else {
        u32x4 pa;
        pa.x = bfpack2(raf[p][0].x, raf[p][0].y); pa.y = bfpack2(raf[p][0].z, raf[p][0].w);
        pa.z = bfpack2(raf[p][1].x, raf[p][1].y); pa.w = bfpack2(raf[p][1].z, raf[p][1].w);
        *(u32x4*)&As[srow[p] * LDT + scolf] = pa;
      }
      u32x4 pw;
      pw.x = bfpack2(rwf[p][0].x, rwf[p][0].y); pw.y = bfpack2(rwf[p][0].z, rwf[p][0].w);
      pw.z = bfpack2(rwf[p][1].x, rwf[p][1].y); pw.w = bfpack2(rwf[p][1].z, rwf[p][1].w);
      *(u32x4*)&Bs[srow[p] * LDT + scolf] = pw;
    }
    __syncthreads();

    const int ktn = (kt + 64 < Kd) ? (kt + 64) : 0;
#pragma unroll
    for (int p = 0; p < 4; ++p) {
      if (A_BF16) {
        rab[p] = *(const u16x8*)((const u16*)Aseg + (rb + srow[p]) * Kd + ktn + scolf);
      } else {
        const float* sa = (const float*)Aseg + (rb + srow[p]) * Kd + ktn + scolf;
        raf[p][0] = *(const f32x4*)sa; raf[p][1] = *(const f32x4*)(sa + 4);
      }
      const float* sw = Wbase + (size_t)srow[p] * Kd + ktn + scolf;
      rwf[p][0] = *(const f32x4*)sw; rwf[p][1] = *(const f32x4*)(sw + 4);
    }

#pragma unroll
    for (int kk = 0; kk < 2; ++kk) {
      bf16x8 af[4], bfr[4];
#pragma unroll
      for (int mi = 0; mi < 4; ++mi)
        af[mi] = *(const bf16x8*)&As[(wm * 64 + mi * 16 + ln) * LDT + kk * 32 + quad * 8];
#pragma unroll
      for (int ni = 0; ni < 4; ++ni)
        bfr[ni] = *(const bf16x8*)&Bs[(wn * 64 + ni * 16 + ln) * LDT + kk * 32 + quad * 8];
#pragma unroll
      for (int mi = 0; mi < 4; ++mi)
#pragma unroll
        for (int ni = 0; ni < 4; ++ni)
          acc[mi][ni] = __builtin_amdgcn_mfma_f32_16x16x32_bf16(af[mi], bfr[ni], acc[mi][ni], 0, 0, 0);
    }
    __syncthreads();
  }

  // epilogue: C/D layout col=lane&15, row=quad*4+reg
#pragma unroll
  for (int ni = 0; ni < 4; ++ni) {
    const int gc = bn * 128 + wn * 64 + ni * 16 + ln;
    const float bval = bias[gc];
#pragma unroll
    for (int mi = 0; mi < 4; ++mi) {
      const int gr = bm * 128 + wm * 64 + mi * 16 + quad * 4;
#pragma unroll
      for (int r = 0; r < 4; ++r) {
        const float v = (acc[mi][ni][r] + bval) * scale;
        if (OUT_BF16)
          ((u16*)Cout)[(size_t)(gr + r) * N + gc] = bf16of(v);
        else
          ((float*)Cout)[(size_t)(gr + r) * N + gc] = v;
      }
    }
  }
}

// ---------------------------------------------------------------------------
// Transpose vcat (b*3072+l, h*32+d) -> vT[(b,h,d), chunk-permuted l]
// pi within each 64-key chunk: pi(lc) = (lc&15)*4 + (lc>>4).
// Gather T[d][x + 16u] (u=0..3) -> contiguous u16x4 store at x*4.
// ---------------------------------------------------------------------------
__global__ __launch_bounds__(256)
void transpose_v_kernel(const u16* __restrict__ vcat, u16* __restrict__ vT) {
  __shared__ u16 T[32][132];
  const int tid = threadIdx.x;
  const int l0  = blockIdx.x * 128;
  const int bh  = blockIdx.y;
  const int b   = bh >> 5, h = bh & 31;

#pragma unroll
  for (int j = 0; j < 4; ++j) {
    const int c = tid + 256 * j;       // 1024 u16x4 chunks
    const int row  = c >> 3;           // 0..127 (l)
    const int col4 = (c & 7) * 4;      // 0..28 (d)
    u16x4 v = *(const u16x4*)&vcat[(size_t)(b * 3072 + l0 + row) * 1024 + h * 32 + col4];
    T[col4 + 0][row] = v.x; T[col4 + 1][row] = v.y;
    T[col4 + 2][row] = v.z; T[col4 + 3][row] = v.w;
  }
  __syncthreads();
#pragma unroll
  for (int j = 0; j < 4; ++j) {
    const int c = tid + 256 * j;       // 1024 output u16x4 chunks
    const int d   = c >> 5;            // 0..31
    const int rem = c & 31;
    const int ch  = rem >> 4;          // 0..1 (which 64-chunk)
    const int x   = rem & 15;          // key&15
    u16x4 v;
    v.x = T[d][ch * 64 + x +  0];
    v.y = T[d][ch * 64 + x + 16];
    v.z = T[d][ch * 64 + x + 32];
    v.w = T[d][ch * 64 + x + 48];
    *(u16x4*)&vT[(size_t)(bh * 32 + d) * 3072 + l0 + ch * 64 + x * 4] = v;
  }
}

// ---------------------------------------------------------------------------
// Attention: 1 wave per block, 32 q-rows, 64-key chunks, NO barriers.
// K/V fragments loaded directly from global (16 B/lane contiguous),
// register-prefetched one chunk ahead. Only LDS use: P round-trip,
// b64 writes (pi-packed) + b128 A-frag reads, 2-way banks max.
// Scores pre-scaled by SCALE*LOG2E in qp -> p = exp2(s). Max-free softmax.
// ---------------------------------------------------------------------------
__global__ __launch_bounds__(64, 2)
void attn_kernel(const u16* __restrict__ qp,
                 const u16* __restrict__ kcat,
                 const u16* __restrict__ vTp,
                 u16* __restrict__ outp) {
  __shared__ u16 Pw[32 * 72];

  const int lane = threadIdx.x;
  const int ln   = lane & 15;
  const int quad = lane >> 4;
  const int bid  = blockIdx.x;
  const int bh   = bid >> 5;          // 0..63
  const int qt   = bid & 31;          // 0..31
  const int b    = bh >> 5;
  const int h    = bh & 31;
  const int q0   = qt * 32;

  // Q A-frags from global (A[m=ln][k=quad*8+j], k = head dim)
  bf16x8 qf[2];
#pragma unroll
  for (int mf = 0; mf < 2; ++mf)
    qf[mf] = *(const bf16x8*)&qp[(size_t)(b * 1024 + q0 + mf * 16 + ln) * 1024 + h * 32 + quad * 8];

  float l_run[2][4];
  f32x4 acc[2][2];
#pragma unroll
  for (int mf = 0; mf < 2; ++mf) {
#pragma unroll
    for (int r = 0; r < 4; ++r) l_run[mf][r] = 0.f;
#pragma unroll
    for (int df = 0; df < 2; ++df) acc[mf][df] = (f32x4){0.f, 0.f, 0.f, 0.f};
  }

  const u16* kbase = kcat + (size_t)(b * 3072) * 1024 + h * 32;
  const u16* vbase = vTp + (size_t)(bh * 32) * 3072;

  bf16x8 kf[4], vf[4], kn[4], vn[4];
#pragma unroll
  for (int nf = 0; nf < 4; ++nf)
    kf[nf] = *(const bf16x8*)&kbase[(size_t)(nf * 16 + ln) * 1024 + quad * 8];
#pragma unroll
  for (int kk = 0; kk < 2; ++kk)
#pragma unroll
    for (int df = 0; df < 2; ++df)
      vf[kk * 2 + df] = *(const bf16x8*)&vbase[(size_t)(df * 16 + ln) * 3072 + kk * 32 + quad * 8];

  for (int c0 = 0; c0 < 3072; c0 += 64) {
    // prefetch next chunk (wrap to 0 on last iter, harmless)
    const int cn = (c0 + 64 < 3072) ? (c0 + 64) : 0;
#pragma unroll
    for (int nf = 0; nf < 4; ++nf)
      kn[nf] = *(const bf16x8*)&kbase[(size_t)(cn + nf * 16 + ln) * 1024 + quad * 8];
#pragma unroll
    for (int kk = 0; kk < 2; ++kk)
#pragma unroll
      for (int df = 0; df < 2; ++df)
        vn[kk * 2 + df] = *(const bf16x8*)&vbase[(size_t)(df * 16 + ln) * 3072 + cn + kk * 32 + quad * 8];

    // S = Q K^T (K-dim = HD = 32)
    f32x4 s[2][4];
#pragma unroll
    for (int mf = 0; mf < 2; ++mf)
#pragma unroll
      for (int nf = 0; nf < 4; ++nf)
        s[mf][nf] = __builtin_amdgcn_mfma_f32_16x16x32_bf16(qf[mf], kf[nf],
                                                            (f32x4){0.f, 0.f, 0.f, 0.f}, 0, 0, 0);

    // softmax numerator; P stored pi-permuted: Pw[q][ln*4 + nf] -> b64 writes
#pragma unroll
    for (int mf = 0; mf < 2; ++mf) {
      float rs[4];
#pragma unroll
      for (int r = 0; r < 4; ++r) {
        const float p0 = exp2f(s[mf][0][r]);
        const float p1 = exp2f(s[mf][1][r]);
        const float p2 = exp2f(s[mf][2][r]);
        const float p3 = exp2f(s[mf][3][r]);
        rs[r] = (p0 + p1) + (p2 + p3);
        u16x4 pk;
        pk.x = bf16of(p0); pk.y = bf16of(p1); pk.z = bf16of(p2); pk.w = bf16of(p3);
        *(u16x4*)&Pw[(mf * 16 + quad * 4 + r) * 72 + ln * 4] = pk;
      }
#pragma unroll
      for (int off = 8; off >= 1; off >>= 1)
#pragma unroll
        for (int r = 0; r < 4; ++r)
          rs[r] += __shfl_xor(rs[r], off, 16);
#pragma unroll
      for (int r = 0; r < 4; ++r) l_run[mf][r] += rs[r];
    }

    // O += P V  (within-wave LDS write->read; in-order per wave)
#pragma unroll
    for (int kk = 0; kk < 2; ++kk)
#pragma unroll
      for (int mf = 0; mf < 2; ++mf) {
        bf16x8 pf = *(const bf16x8*)&Pw[(mf * 16 + ln) * 72 + kk * 32 + quad * 8];
#pragma unroll
        for (int df = 0; df < 2; ++df)
          acc[mf][df] = __builtin_amdgcn_mfma_f32_16x16x32_bf16(pf, vf[kk * 2 + df], acc[mf][df], 0, 0, 0);
      }

#pragma unroll
    for (int i = 0; i < 4; ++i) { kf[i] = kn[i]; vf[i] = vn[i]; }
  }

  // epilogue: bf16 out, layout (b, q, h*32+d)
#pragma unroll
  for (int mf = 0; mf < 2; ++mf)
#pragma unroll
    for (int r = 0; r < 4; ++r) {
      const float inv = 1.0f / l_run[mf][r];
      const size_t orow = (size_t)(b * 1024 + q0 + mf * 16 + quad * 4 + r) * 1024 + h * 32;
#pragma unroll
      for (int df = 0; df < 2; ++df)
        outp[orow + df * 16 + ln] = bf16of(acc[mf][df][r] * inv);
    }
}

// ---------------------------------------------------------------------------
extern "C" void kernel_launch(void* const* d_in, const int* in_sizes, int n_in,
                              void* d_out, int out_size, void* d_ws, size_t ws_size,
                              hipStream_t stream) {
  (void)in_sizes; (void)n_in; (void)out_size; (void)ws_size;
  const float* query  = (const float*)d_in[0];
  const float* key    = (const float*)d_in[1];
  const float* value  = (const float*)d_in[2];
  const float* memory = (const float*)d_in[3];
  const float* Wq = (const float*)d_in[4];
  const float* bq = (const float*)d_in[5];
  const float* Wk = (const float*)d_in[6];
  const float* bk = (const float*)d_in[7];
  const float* Wv = (const float*)d_in[8];
  const float* bv = (const float*)d_in[9];
  const float* Wo = (const float*)d_in[10];
  const float* bo = (const float*)d_in[11];
  float* out = (float*)d_out;

  // workspace layout (44 MB total)
  char* ws = (char*)d_ws;
  u16* qp      = (u16*)(ws);                                   //  4 MB
  u16* kcat    = (u16*)(ws + (size_t)4  * 1024 * 1024);        // 12 MB
  u16* vcat    = (u16*)(ws + (size_t)16 * 1024 * 1024);        // 12 MB
  u16* vT      = (u16*)(ws + (size_t)28 * 1024 * 1024);        // 12 MB
  u16* attn_bf = (u16*)(ws + (size_t)40 * 1024 * 1024);        //  4 MB

  dim3 blk(256);
  // qp = (query Wq^T + bq) * SCALE * LOG2E  (pre-scaled for exp2 softmax)
  gemm_nt_kernel<0, 1><<<dim3(16, 8), blk, 0, stream>>>(query, 1024, nullptr, 0, Wq, bq, qp, SCALE_ * LOG2E_);
  // kcat = concat(key, memory) Wk^T + bk
  gemm_nt_kernel<0, 1><<<dim3(48, 8), blk, 0, stream>>>(key, 2048, memory, 1024, Wk, bk, kcat, 1.0f);
  // vcat = concat(value, memory) Wv^T + bv
  gemm_nt_kernel<0, 1><<<dim3(48, 8), blk, 0, stream>>>(value, 2048, memory, 1024, Wv, bv, vcat, 1.0f);
  // vT (pi-permuted) for PV B-operand
  transpose_v_kernel<<<dim3(24, 64), blk, 0, stream>>>(vcat, vT);
  // attention: 2048 single-wave blocks (64 bh x 32 q-tiles), no barriers
  attn_kernel<<<dim3(2048), dim3(64), 0, stream>>>(qp, kcat, vT, attn_bf);
  // out = attn Wo^T + bo
  gemm_nt_kernel<1, 0><<<dim3(16, 8), blk, 0, stream>>>(attn_bf, 2048, nullptr, 0, Wo, bo, (void*)out, 1.0f);
}

// Round 3
// 303.367 us; speedup vs baseline: 1.2153x; 1.0749x over previous
//
#include <hip/hip_runtime.h>

// ---------------------------------------------------------------------------
// MemoryAttention: B=2 Q=1024 K=2048 M=1024 E=1024 H=32 HD=32
// Pipeline:
//   prep  : fp32 -> bf16, panel-major XOR-swizzled layout for GEMM staging
//           dst[(kt*R+row)*64 + (c^(row&7))*8 + j] = src[row][kt*64+c*8+j]
//   gemm  : m97-style 128x128 (or 64x128) tile, BK=64, global_load_lds(16B),
//           swizzled ds_read_b128 (2-way banks = free)
//   qp    = (query Wq^T + bq) * SCALE * LOG2E      (bf16 row-major)
//   kcat  = concat(key,mem) Wk^T + bk              (bf16 row-major)
//   vcat  = concat(value,mem) Wv^T + bv            (bf16 row-major)
//   vT    = per-(b,h) transpose of vcat, key axis pi-permuted
//   attn  = softmax(qp kcat^T) vcat  -> written swizzled panel-major
//   out   = attn Wo^T + bo                         (fp32 -> d_out)
// attn: 4 waves/block split the 3072 keys; max-free softmax => partials are
// plain sums; row-sums via MFMA with all-ones B fragment; combine in LDS.
// ---------------------------------------------------------------------------

typedef float  f32x4  __attribute__((ext_vector_type(4)));
typedef short  bf16x8 __attribute__((ext_vector_type(8)));
typedef unsigned int   u32;
typedef unsigned short u16;
typedef u32 u32x2 __attribute__((ext_vector_type(2)));
typedef u32 u32x4 __attribute__((ext_vector_type(4)));
typedef u16 u16x4 __attribute__((ext_vector_type(4)));

#define SCALE_  0.17677669529663687f   // 32^-0.5
#define LOG2E_  1.4426950408889634f

static __device__ __forceinline__ u32 bfpack2(float lo, float hi) {
  u32 a = __builtin_bit_cast(u32, lo) + 0x8000u;
  u32 b = __builtin_bit_cast(u32, hi) + 0x8000u;
  return __builtin_amdgcn_perm(b, a, 0x07060302u);
}
static __device__ __forceinline__ u16 bf16of(float x) {
  return (u16)((__builtin_bit_cast(u32, x) + 0x8000u) >> 16);
}
static __device__ __forceinline__ void gld_lds16(const u16* g, u16* l) {
  __builtin_amdgcn_global_load_lds(
      (const __attribute__((address_space(1))) void*)g,
      (__attribute__((address_space(3))) void*)l, 16, 0, 0);
}

// ---------------------------------------------------------------------------
// prep: fp32 -> bf16 swizzled panel-major, 8 tensors, 64 rows/block
// ---------------------------------------------------------------------------
__global__ __launch_bounds__(256)
void prep_kernel(const float* __restrict__ q, const float* __restrict__ k,
                 const float* __restrict__ v, const float* __restrict__ m,
                 const float* __restrict__ wq, const float* __restrict__ wk,
                 const float* __restrict__ wv, const float* __restrict__ wo,
                 u16* qs, u16* ks, u16* vs, u16* ms,
                 u16* wqs, u16* wks, u16* wvs, u16* wos) {
  const int bid = blockIdx.x;
  const float* src; u16* dst; int R, r0;
  if (bid < 32)       { src = q;  dst = qs;  R = 2048; r0 = bid * 64; }
  else if (bid < 96)  { src = k;  dst = ks;  R = 4096; r0 = (bid - 32) * 64; }
  else if (bid < 160) { src = v;  dst = vs;  R = 4096; r0 = (bid - 96) * 64; }
  else if (bid < 192) { src = m;  dst = ms;  R = 2048; r0 = (bid - 160) * 64; }
  else if (bid < 208) { src = wq; dst = wqs; R = 1024; r0 = (bid - 192) * 64; }
  else if (bid < 224) { src = wk; dst = wks; R = 1024; r0 = (bid - 208) * 64; }
  else if (bid < 240) { src = wv; dst = wvs; R = 1024; r0 = (bid - 224) * 64; }
  else                { src = wo; dst = wos; R = 1024; r0 = (bid - 240) * 64; }

  for (int i = 0; i < 32; ++i) {
    const int idx = i * 256 + threadIdx.x;    // 0..8191 = 64 rows x 128 chunks
    const int row = idx >> 7;
    const int cal = idx & 127;
    const int kt = cal >> 3, c = cal & 7;
    const float* s = src + (size_t)(r0 + row) * 1024 + kt * 64 + c * 8;
    f32x4 a = *(const f32x4*)s, b = *(const f32x4*)(s + 4);
    u32x4 p;
    p.x = bfpack2(a.x, a.y); p.y = bfpack2(a.z, a.w);
    p.z = bfpack2(b.x, b.y); p.w = bfpack2(b.z, b.w);
    *(u32x4*)&dst[((size_t)kt * R + r0 + row) * 64 + ((c ^ (row & 7)) << 3)] = p;
  }
}

// ---------------------------------------------------------------------------
// GEMM: C[m,n] = (sum_k A[m,k]*W[n,k] + bias[n]) * scale
// A from two per-batch segments (panel-major swizzled, strides R0/R1).
// MT x 128 tile, BK=64, 4 waves (2x2), global_load_lds staging.
// ---------------------------------------------------------------------------
template <int MT, int OUT_BF16>
__global__ __launch_bounds__(256)
void gemm_sw_kernel(const u16* __restrict__ A0, int L0, int R0,
                    const u16* __restrict__ A1, int L1, int R1,
                    const u16* __restrict__ Wsw,
                    const float* __restrict__ bias,
                    void* __restrict__ Cout, float scale) {
  constexpr int MI = MT / 32;          // mi frags per wave
  __shared__ u16 As[MT * 64];
  __shared__ u16 Bs[128 * 64];

  const int tid  = threadIdx.x;
  const int lane = tid & 63;
  const int wave = tid >> 6;
  const int ln   = lane & 15;
  const int quad = lane >> 4;
  const int wm   = wave >> 1;
  const int wn   = wave & 1;
  const int bm = blockIdx.x, bn = blockIdx.y;

  const int gr0 = bm * MT;
  const int per = L0 + L1;
  const int bb  = gr0 / per;
  const int i0  = gr0 - bb * per;
  const u16* Abase; size_t row0; int RA;
  if (i0 < L0) { Abase = A0; row0 = (size_t)bb * L0 + i0; RA = R0; }
  else         { Abase = A1; row0 = (size_t)bb * L1 + (i0 - L0); RA = R1; }

  f32x4 acc[MI][4];
#pragma unroll
  for (int i = 0; i < MI; ++i)
#pragma unroll
    for (int j = 0; j < 4; ++j)
      acc[i][j] = (f32x4){0.f, 0.f, 0.f, 0.f};

  for (int kt = 0; kt < 16; ++kt) {
    const u16* Ag = Abase + ((size_t)kt * RA + row0) * 64;
    const u16* Bg = Wsw + ((size_t)kt * 1024 + bn * 128) * 64;
#pragma unroll
    for (int r = 0; r < MI; ++r) {
      const int ii = wave * MI + r;
      gld_lds16(Ag + ii * 512 + lane * 8, &As[ii * 512]);
    }
#pragma unroll
    for (int r = 0; r < 4; ++r) {
      const int ii = wave * 4 + r;
      gld_lds16(Bg + ii * 512 + lane * 8, &Bs[ii * 512]);
    }
    __syncthreads();

#pragma unroll
    for (int kk = 0; kk < 2; ++kk) {
      const int cp = ((kk * 4) ^ (ln & 7));   // quad folded below
      bf16x8 af[MI], bfr[4];
#pragma unroll
      for (int mi = 0; mi < MI; ++mi) {
        const int row = wm * (MI * 16) + mi * 16 + ln;
        af[mi] = *(const bf16x8*)&As[row * 64 + (((kk * 4 + quad) ^ (ln & 7)) << 3)];
      }
#pragma unroll
      for (int ni = 0; ni < 4; ++ni) {
        const int row = wn * 64 + ni * 16 + ln;
        bfr[ni] = *(const bf16x8*)&Bs[row * 64 + (((kk * 4 + quad) ^ (ln & 7)) << 3)];
      }
      (void)cp;
#pragma unroll
      for (int mi = 0; mi < MI; ++mi)
#pragma unroll
        for (int ni = 0; ni < 4; ++ni)
          acc[mi][ni] = __builtin_amdgcn_mfma_f32_16x16x32_bf16(af[mi], bfr[ni], acc[mi][ni], 0, 0, 0);
    }
    __syncthreads();
  }

  // epilogue: C/D layout col=lane&15, row=quad*4+reg
#pragma unroll
  for (int ni = 0; ni < 4; ++ni) {
    const int gc = bn * 128 + wn * 64 + ni * 16 + ln;
    const float bval = bias[gc];
#pragma unroll
    for (int mi = 0; mi < MI; ++mi) {
      const int gr = bm * MT + wm * (MI * 16) + mi * 16 + quad * 4;
#pragma unroll
      for (int r = 0; r < 4; ++r) {
        const float vv = (acc[mi][ni][r] + bval) * scale;
        if (OUT_BF16)
          ((u16*)Cout)[(size_t)(gr + r) * 1024 + gc] = bf16of(vv);
        else
          ((float*)Cout)[(size_t)(gr + r) * 1024 + gc] = vv;
      }
    }
  }
}

// ---------------------------------------------------------------------------
// Transpose vcat (b*3072+l, h*32+d) -> vT[(b,h,d), chunk-permuted l]
// pi within each 64-key chunk: pi(lc) = (lc&15)*4 + (lc>>4).
// ---------------------------------------------------------------------------
__global__ __launch_bounds__(256)
void transpose_v_kernel(const u16* __restrict__ vcat, u16* __restrict__ vT) {
  __shared__ u16 T[32][132];
  const int tid = threadIdx.x;
  const int l0  = blockIdx.x * 128;
  const int bh  = blockIdx.y;
  const int b   = bh >> 5, h = bh & 31;

#pragma unroll
  for (int j = 0; j < 4; ++j) {
    const int c = tid + 256 * j;
    const int row  = c >> 3;
    const int col4 = (c & 7) * 4;
    u16x4 v = *(const u16x4*)&vcat[(size_t)(b * 3072 + l0 + row) * 1024 + h * 32 + col4];
    T[col4 + 0][row] = v.x; T[col4 + 1][row] = v.y;
    T[col4 + 2][row] = v.z; T[col4 + 3][row] = v.w;
  }
  __syncthreads();
#pragma unroll
  for (int j = 0; j < 4; ++j) {
    const int c = tid + 256 * j;
    const int d   = c >> 5;
    const int rem = c & 31;
    const int ch  = rem >> 4;
    const int x   = rem & 15;
    u16x4 v;
    v.x = T[d][ch * 64 + x +  0];
    v.y = T[d][ch * 64 + x + 16];
    v.z = T[d][ch * 64 + x + 32];
    v.w = T[d][ch * 64 + x + 48];
    *(u16x4*)&vT[(size_t)(bh * 32 + d) * 3072 + l0 + ch * 64 + x * 4] = v;
  }
}

// ---------------------------------------------------------------------------
// Attention: block = (bh, 32 q-rows), 4 waves split the 3072 keys (12 chunks
// of 64 each). Max-free softmax (scores pre-scaled by SCALE*LOG2E in qp).
// Row sums via MFMA with all-ones B frag. Combine partials in LDS.
// Grid: bid = qt*64 + bh  =>  XCD = bid%8 = bh%8 (L2-pins K/V per XCD).
// Output written in swizzled panel-major layout for the final GEMM.
// ---------------------------------------------------------------------------
__global__ __launch_bounds__(256, 4)
void attn_kernel(const u16* __restrict__ qp,
                 const u16* __restrict__ kcat,
                 const u16* __restrict__ vTp,
                 u16* __restrict__ attn_sw) {
  __shared__ u16 PwAll[4 * 32 * 72];     // 18432 B; reused for combine

  const int tid  = threadIdx.x;
  const int lane = tid & 63;
  const int wave = tid >> 6;
  const int ln   = lane & 15;
  const int quad = lane >> 4;
  const int bid  = blockIdx.x;
  const int bh   = bid & 63;
  const int qt   = bid >> 6;
  const int b    = bh >> 5;
  const int h    = bh & 31;
  const int q0   = qt * 32;

  bf16x8 qf[2];
#pragma unroll
  for (int mf = 0; mf < 2; ++mf)
    qf[mf] = *(const bf16x8*)&qp[(size_t)(b * 1024 + q0 + mf * 16 + ln) * 1024 + h * 32 + quad * 8];

  f32x4 acc[2][2], accS[2];
#pragma unroll
  for (int mf = 0; mf < 2; ++mf) {
    accS[mf] = (f32x4){0.f, 0.f, 0.f, 0.f};
#pragma unroll
    for (int df = 0; df < 2; ++df) acc[mf][df] = (f32x4){0.f, 0.f, 0.f, 0.f};
  }
  bf16x8 ones;
#pragma unroll
  for (int i = 0; i < 8; ++i) ones[i] = (short)0x3F80;   // bf16 1.0

  const u16* kbase = kcat + (size_t)(b * 3072) * 1024 + h * 32;
  const u16* vbase = vTp + (size_t)(bh * 32) * 3072;
  u16* Pw = &PwAll[wave * (32 * 72)];

  for (int ci = 0; ci < 12; ++ci) {
    const int c0 = (wave * 12 + ci) * 64;

    bf16x8 kf[4], vf[4];
#pragma unroll
    for (int nf = 0; nf < 4; ++nf)
      kf[nf] = *(const bf16x8*)&kbase[(size_t)(c0 + nf * 16 + ln) * 1024 + quad * 8];
#pragma unroll
    for (int kk = 0; kk < 2; ++kk)
#pragma unroll
      for (int df = 0; df < 2; ++df)
        vf[kk * 2 + df] = *(const bf16x8*)&vbase[(size_t)(df * 16 + ln) * 3072 + c0 + kk * 32 + quad * 8];

    // S = Q K^T
    f32x4 s[2][4];
#pragma unroll
    for (int mf = 0; mf < 2; ++mf)
#pragma unroll
      for (int nf = 0; nf < 4; ++nf)
        s[mf][nf] = __builtin_amdgcn_mfma_f32_16x16x32_bf16(qf[mf], kf[nf],
                                                            (f32x4){0.f, 0.f, 0.f, 0.f}, 0, 0, 0);

    // P = exp2(S), pi-packed into LDS (b64 writes, stride 72)
#pragma unroll
    for (int mf = 0; mf < 2; ++mf)
#pragma unroll
      for (int r = 0; r < 4; ++r) {
        const float p0 = __builtin_exp2f(s[mf][0][r]);
        const float p1 = __builtin_exp2f(s[mf][1][r]);
        const float p2 = __builtin_exp2f(s[mf][2][r]);
        const float p3 = __builtin_exp2f(s[mf][3][r]);
        u32x2 pk;
        pk.x = bfpack2(p0, p1);
        pk.y = bfpack2(p2, p3);
        *(u32x2*)&Pw[(mf * 16 + quad * 4 + r) * 72 + ln * 4] = pk;
      }

    // O += P V ; rowsum += P * ones  (within-wave LDS write->read)
#pragma unroll
    for (int kk = 0; kk < 2; ++kk)
#pragma unroll
      for (int mf = 0; mf < 2; ++mf) {
        bf16x8 pf = *(const bf16x8*)&Pw[(mf * 16 + ln) * 72 + kk * 32 + quad * 8];
        accS[mf] = __builtin_amdgcn_mfma_f32_16x16x32_bf16(pf, ones, accS[mf], 0, 0, 0);
#pragma unroll
        for (int df = 0; df < 2; ++df)
          acc[mf][df] = __builtin_amdgcn_mfma_f32_16x16x32_bf16(pf, vf[kk * 2 + df], acc[mf][df], 0, 0, 0);
      }
  }

  // ---- cross-wave combine ----
  __syncthreads();
  f32x4* CA = (f32x4*)PwAll;             // [w][mf][df][lane] : 16 KB
  f32x4* CS = (f32x4*)&PwAll[8192];      // [w][mf][quad]     : 512 B
#pragma unroll
  for (int mf = 0; mf < 2; ++mf) {
#pragma unroll
    for (int df = 0; df < 2; ++df)
      CA[((wave * 2 + mf) * 2 + df) * 64 + lane] = acc[mf][df];
    if (ln == 0) CS[(wave * 2 + mf) * 4 + quad] = accS[mf];
  }
  __syncthreads();

  if (wave == 0) {
    const int j = ln & 7, chi = ln >> 3;
#pragma unroll
    for (int mf = 0; mf < 2; ++mf) {
      f32x4 l = CS[(0 + mf) * 4 + quad];
#pragma unroll
      for (int w = 1; w < 4; ++w) l += CS[((w * 2) + mf) * 4 + quad];
      f32x4 inv;
#pragma unroll
      for (int r = 0; r < 4; ++r) inv[r] = 1.0f / l[r];
#pragma unroll
      for (int df = 0; df < 2; ++df) {
        f32x4 t = CA[((0 + mf) * 2 + df) * 64 + lane];
#pragma unroll
        for (int w = 1; w < 4; ++w) t += CA[(((w * 2) + mf) * 2 + df) * 64 + lane];
        const int c = (h & 1) * 4 + df * 2 + chi;
#pragma unroll
        for (int r = 0; r < 4; ++r) {
          const int row = b * 1024 + q0 + mf * 16 + quad * 4 + r;
          const int cp  = c ^ ((quad * 4 + r) & 7);
          attn_sw[((size_t)(h >> 1) * 2048 + row) * 64 + cp * 8 + j] = bf16of(t[r] * inv[r]);
        }
      }
    }
  }
}

// ---------------------------------------------------------------------------
extern "C" void kernel_launch(void* const* d_in, const int* in_sizes, int n_in,
                              void* d_out, int out_size, void* d_ws, size_t ws_size,
                              hipStream_t stream) {
  (void)in_sizes; (void)n_in; (void)out_size; (void)ws_size;
  const float* query  = (const float*)d_in[0];
  const float* key    = (const float*)d_in[1];
  const float* value  = (const float*)d_in[2];
  const float* memory = (const float*)d_in[3];
  const float* Wq = (const float*)d_in[4];
  const float* bq = (const float*)d_in[5];
  const float* Wk = (const float*)d_in[6];
  const float* bk = (const float*)d_in[7];
  const float* Wv = (const float*)d_in[8];
  const float* bv = (const float*)d_in[9];
  const float* Wo = (const float*)d_in[10];
  const float* bo = (const float*)d_in[11];
  float* out = (float*)d_out;

  // workspace layout (76 MB)
  char* ws = (char*)d_ws;
  const size_t MB = 1024 * 1024;
  u16* query_sw = (u16*)(ws + 0 * MB);    //  4 MB (2048 rows)
  u16* key_sw   = (u16*)(ws + 4 * MB);    //  8 MB (4096 rows)
  u16* value_sw = (u16*)(ws + 12 * MB);   //  8 MB (4096 rows)
  u16* mem_sw   = (u16*)(ws + 20 * MB);   //  4 MB (2048 rows)
  u16* Wq_sw    = (u16*)(ws + 24 * MB);   //  2 MB
  u16* Wk_sw    = (u16*)(ws + 26 * MB);   //  2 MB
  u16* Wv_sw    = (u16*)(ws + 28 * MB);   //  2 MB
  u16* Wo_sw    = (u16*)(ws + 30 * MB);   //  2 MB
  u16* qp       = (u16*)(ws + 32 * MB);   //  4 MB
  u16* kcat     = (u16*)(ws + 36 * MB);   // 12 MB
  u16* vcat     = (u16*)(ws + 48 * MB);   // 12 MB
  u16* vT       = (u16*)(ws + 60 * MB);   // 12 MB
  u16* attn_sw  = (u16*)(ws + 72 * MB);   //  4 MB

  dim3 blk(256);
  prep_kernel<<<dim3(256), blk, 0, stream>>>(query, key, value, memory, Wq, Wk, Wv, Wo,
                                             query_sw, key_sw, value_sw, mem_sw,
                                             Wq_sw, Wk_sw, Wv_sw, Wo_sw);
  // qp = (query Wq^T + bq) * SCALE * LOG2E
  gemm_sw_kernel<64, 1><<<dim3(32, 8), blk, 0, stream>>>(
      query_sw, 2048, 2048, nullptr, 0, 0, Wq_sw, bq, qp, SCALE_ * LOG2E_);
  // kcat = concat(key, memory) Wk^T + bk
  gemm_sw_kernel<128, 1><<<dim3(48, 8), blk, 0, stream>>>(
      key_sw, 2048, 4096, mem_sw, 1024, 2048, Wk_sw, bk, kcat, 1.0f);
  // vcat = concat(value, memory) Wv^T + bv
  gemm_sw_kernel<128, 1><<<dim3(48, 8), blk, 0, stream>>>(
      value_sw, 2048, 4096, mem_sw, 1024, 2048, Wv_sw, bv, vcat, 1.0f);
  // vT (pi-permuted) for PV B-operand
  transpose_v_kernel<<<dim3(24, 64), blk, 0, stream>>>(vcat, vT);
  // attention -> swizzled panel-major A for final GEMM
  attn_kernel<<<dim3(2048), blk, 0, stream>>>(qp, kcat, vT, attn_sw);
  // out = attn Wo^T + bo
  gemm_sw_kernel<64, 0><<<dim3(32, 8), blk, 0, stream>>>(
      attn_sw, 2048, 2048, nullptr, 0, 0, Wo_sw, bo, (void*)out, 1.0f);
}